// Round 19
// baseline (124.459 us; speedup 1.0000x reference)
//
#include <hip/hip_runtime.h>
#include <cstdint>
#include <cstddef>

typedef __bf16 bf16;
typedef __attribute__((ext_vector_type(8))) __bf16 bf16x8;
typedef __attribute__((ext_vector_type(4))) __bf16 bf16x4;
typedef __attribute__((ext_vector_type(4))) float f32x4;

constexpr int kS = 2048;
constexpr int kH = 16;
constexpr int kD = 64;

__device__ __forceinline__ void gload16(const bf16* g, bf16* l) {
  __builtin_amdgcn_global_load_lds((const __attribute__((address_space(1))) void*)g,
                                   (__attribute__((address_space(3))) void*)l, 16, 0, 0);
}

// ---------------- cast fp32 -> bf16 (x + 4 weights), 8 floats/thread ----------------
__global__ __launch_bounds__(256) void cast_all_kernel(
    const float* __restrict__ x, const float* __restrict__ wq, const float* __restrict__ wk,
    const float* __restrict__ wv, const float* __restrict__ wo,
    bf16* __restrict__ xb, bf16* __restrict__ wqb, bf16* __restrict__ wkb,
    bf16* __restrict__ wvb, bf16* __restrict__ wob) {
  int idx = blockIdx.x * 256 + threadIdx.x;   // 1M threads, 8 floats each
  const float* src; bf16* dst; int i;
  if (idx < (1 << 19)) { src = x; dst = xb; i = idx << 3; }
  else {
    int r = idx - (1 << 19);
    int t = r >> 17;
    i = (r & ((1 << 17) - 1)) << 3;
    src = (t == 0) ? wq : (t == 1) ? wk : (t == 2) ? wv : wo;
    dst = (t == 0) ? wqb : (t == 1) ? wkb : (t == 2) ? wvb : wob;
  }
  float4 v0 = *(const float4*)(src + i);
  float4 v1 = *(const float4*)(src + i + 4);
  bf16x8 o;
  o[0] = (bf16)v0.x; o[1] = (bf16)v0.y; o[2] = (bf16)v0.z; o[3] = (bf16)v0.w;
  o[4] = (bf16)v1.x; o[5] = (bf16)v1.y; o[6] = (bf16)v1.z; o[7] = (bf16)v1.w;
  *(bf16x8*)(dst + i) = o;
}

// PROVEN GEMM structure (r6/r8/r14) + r18 XCD-local remap (L2-fit working
// set broke the "~490TF plateau": it was L2-locality, not loop structure).
// LDS granule swizzle: read quad (lr&1)*4+(lg^((lr>>1)&3)); source
// pre-permuted to match (conflicts=0).

#define GSTAGE(BUF, KT)                                    \
  gload16(aP0 + (KT), &As[BUF][(w * 64 + l) * 8]);         \
  gload16(aP1 + (KT), &As[BUF][((4 + w) * 64 + l) * 8]);   \
  gload16(bP0 + (KT), &Bs[BUF][(w * 64 + l) * 8]);         \
  gload16(bP1 + (KT), &Bs[BUF][((4 + w) * 64 + l) * 8]);

// ---------------- fused QKV GEMM + RoPE + layout transforms ----------------
// q: [B,H,S,D]; k: [B,H,S,D] PRE-SCALED by 0.125*log2(e) (softmax fold);
// v: fully MFMA-tiled [bh][kv128-blk][chunk(c*4+f)][lane][8] so attn reads
//    V direct global->reg, 1KB-coalesced per instruction (r19).
// r18 remap: XCD x owns an (8-mblk x 4-npanel) rectangle across all 3
// outputs -> per-XCD working set 5MB (L2-adjacent). Bijective on 768.
__global__ __launch_bounds__(256) void gemm_qkv(const bf16* __restrict__ A,
                                                const bf16* __restrict__ wq,
                                                const bf16* __restrict__ wk,
                                                const bf16* __restrict__ wv,
                                                bf16* __restrict__ qo,
                                                bf16* __restrict__ ko,
                                                bf16* __restrict__ vto) {
  __shared__ bf16 As[2][128 * 32];
  __shared__ bf16 Bs[2][128 * 32];
  const int tid = threadIdx.x;
  const int w = tid >> 6, l = tid & 63;
  const int wr = w >> 1, wc = w & 1;
  const int lr = l & 15, lg = l >> 4;

  const int xcd = blockIdx.x & 7;
  const int idx = blockIdx.x >> 3;          // 0..95 within XCD
  const int which = idx >> 5;               // 0=q 1=k 2=v
  const int rem = idx & 31;
  const int mblk = ((xcd >> 1) << 3) + (rem >> 2);
  const int npanel = ((xcd & 1) << 2) + (rem & 3);
  const int m0 = mblk * 128;
  const int n0 = npanel * 128;
  const bf16* Bw = (which == 0) ? wq : (which == 1) ? wk : wv;

  const int srow = l >> 2;
  const int skcol = ((l & 3) ^ ((l >> 3) & 3)) << 3;   // swizzled source chunk
  const int K = 1024;

  const bf16* aP0 = A + (size_t)(m0 + w * 16 + srow) * K + skcol;
  const bf16* aP1 = A + (size_t)(m0 + 64 + w * 16 + srow) * K + skcol;
  const bf16* bP0 = Bw + (size_t)(n0 + w * 16 + srow) * K + skcol;
  const bf16* bP1 = Bw + (size_t)(n0 + 64 + w * 16 + srow) * K + skcol;

  f32x4 acc[4][4] = {};
  const int ca = (lg ^ ((lr >> 1) & 3)) * 8;           // swizzled read chunk

  GSTAGE(0, 0)
  __syncthreads();
  int cur = 0;
  for (int kt = 0; kt < K; kt += 32) {
    if (kt + 32 < K) { GSTAGE(cur ^ 1, kt + 32) }
    bf16x8 af[4], bfg[4];
#pragma unroll
    for (int mi = 0; mi < 4; mi++)
      af[mi] = *(const bf16x8*)&As[cur][(wr * 64 + mi * 16 + lr) * 32 + ca];
#pragma unroll
    for (int ni = 0; ni < 4; ni++)
      bfg[ni] = *(const bf16x8*)&Bs[cur][(wc * 64 + ni * 16 + lr) * 32 + ca];
    __builtin_amdgcn_s_setprio(1);
#pragma unroll
    for (int mi = 0; mi < 4; mi++)
#pragma unroll
      for (int ni = 0; ni < 4; ni++)
        acc[mi][ni] = __builtin_amdgcn_mfma_f32_16x16x32_bf16(af[mi], bfg[ni], acc[mi][ni], 0, 0, 0);
    __builtin_amdgcn_s_setprio(0);
    __syncthreads();
    cur ^= 1;
  }

  float invf_[4];
#pragma unroll
  for (int ni = 0; ni < 4; ni++) {
    int d31 = ((n0 + wc * 64 + ni * 16 + lr) & 63) & 31;
    invf_[ni] = exp2f((float)d31 * -0.41524100480466348f);   // 10000^(-(d&31)/32)
  }

#pragma unroll
  for (int mi = 0; mi < 4; mi++) {
#pragma unroll
    for (int ni = 0; ni < 4; ni++) {
#pragma unroll
      for (int r = 0; r < 4; r++) {
        const int m = m0 + wr * 64 + mi * 16 + lg * 4 + r;   // token index
        const int n = n0 + wc * 64 + ni * 16 + lr;           // emb index (h*64+d)
        float v = acc[mi][ni][r];
        const int st = m & 2047;                              // seq position
        const size_t bh = (size_t)(m >> 11) * kH + (n >> 6);
        if (which < 2) {
          float vp = __shfl_xor(v, 1);
          const int d = n & 63;
          float th = (float)st * invf_[ni];
          float sth = __sinf(th), cth = __cosf(th);
          float rv = v * cth + ((d & 1) ? vp : -vp) * sth;
          if (which == 1) rv *= 0.18033688011112042f;        // 0.125*log2(e): softmax fold
          bf16* dst = which ? ko : qo;                       // [B,H,S,D]
          dst[((bh << 11) + st) * kD + d] = (bf16)rv;
        } else {
          // V: fully MFMA-tiled layout. pos carries the 32-chunk permutation.
          int pos = (st & ~31) | (((st >> 2) & 3) << 3) | (((st >> 4) & 1) << 2) | (st & 3);
          const int d = n & 63;
          const int c = d >> 4, lr2 = d & 15;
          const int kvblk = pos >> 7, f = (pos >> 5) & 3, lg2 = (pos >> 3) & 3, j = pos & 7;
          vto[bh * 131072 + (size_t)kvblk * 8192 + (c * 4 + f) * 512 + (lg2 * 16 + lr2) * 8 + j] = (bf16)v;
        }
      }
    }
  }
}

// ---------------- final GEMM C = A @ Wo^T, fp32 out ----------------
// r17 XCD-locality remap (proven): XCD owns m-rows [4x,4x+4) x all 8
// n-panels -> 3MB L2-fit.
__global__ __launch_bounds__(256) void gemm_out(const bf16* __restrict__ A,
                                                const bf16* __restrict__ Bw,
                                                float* __restrict__ Cout) {
  __shared__ bf16 As[2][128 * 32];
  __shared__ bf16 Bs[2][128 * 32];
  const int tid = threadIdx.x;
  const int w = tid >> 6, l = tid & 63;
  const int wr = w >> 1, wc = w & 1;
  const int lr = l & 15, lg = l >> 4;
  const int bid = blockIdx.x;
  const int m0 = (((bid & 7) << 2) + ((bid >> 3) >> 3)) * 128;   // XCD owns 4 m-rows
  const int n0 = ((bid >> 3) & 7) * 128;
  const int K = 1024, N = 1024;

  const int srow = l >> 2;
  const int skcol = ((l & 3) ^ ((l >> 3) & 3)) << 3;

  const bf16* aP0 = A + (size_t)(m0 + w * 16 + srow) * K + skcol;
  const bf16* aP1 = A + (size_t)(m0 + 64 + w * 16 + srow) * K + skcol;
  const bf16* bP0 = Bw + (size_t)(n0 + w * 16 + srow) * K + skcol;
  const bf16* bP1 = Bw + (size_t)(n0 + 64 + w * 16 + srow) * K + skcol;

  f32x4 acc[4][4] = {};
  const int ca = (lg ^ ((lr >> 1) & 3)) * 8;

  GSTAGE(0, 0)
  __syncthreads();
  int cur = 0;
  for (int kt = 0; kt < K; kt += 32) {
    if (kt + 32 < K) { GSTAGE(cur ^ 1, kt + 32) }
    bf16x8 af[4], bfg[4];
#pragma unroll
    for (int mi = 0; mi < 4; mi++)
      af[mi] = *(const bf16x8*)&As[cur][(wr * 64 + mi * 16 + lr) * 32 + ca];
#pragma unroll
    for (int ni = 0; ni < 4; ni++)
      bfg[ni] = *(const bf16x8*)&Bs[cur][(wc * 64 + ni * 16 + lr) * 32 + ca];
    __builtin_amdgcn_s_setprio(1);
#pragma unroll
    for (int mi = 0; mi < 4; mi++)
#pragma unroll
      for (int ni = 0; ni < 4; ni++)
        acc[mi][ni] = __builtin_amdgcn_mfma_f32_16x16x32_bf16(af[mi], bfg[ni], acc[mi][ni], 0, 0, 0);
    __builtin_amdgcn_s_setprio(0);
    __syncthreads();
    cur ^= 1;
  }

#pragma unroll
  for (int mi = 0; mi < 4; mi++)
#pragma unroll
    for (int ni = 0; ni < 4; ni++)
#pragma unroll
      for (int r = 0; r < 4; r++) {
        const int m = m0 + wr * 64 + mi * 16 + lg * 4 + r;
        const int n = n0 + wc * 64 + ni * 16 + lr;
        Cout[(size_t)m * N + n] = acc[mi][ni][r];
      }
}

// ---------------- flash attention, causal, KVBLK=128, V direct-from-global ----------------
// K LDS-staged (2-buf, 4 gloads/wave); V read global->reg via the MFMA-tiled
// layout: 1KB-coalesced per bf16x8 instruction, L2-resident (1MB/XCD).
// Halves LDS traffic (only K re-read by 4 waves) and the per-barrier drain.
// LDS 32KB + ~140 VGPR -> 3 blocks/CU (launch_bounds(256,3)).
// Softmax: K pre-scaled -> p = exp2(sa) raw, no max tracking.

#define STAGE(BUF, KV0)                                                                  \
  {                                                                                      \
    _Pragma("unroll") for (int j_ = 0; j_ < 4; j_++) {                                   \
      const int ch_ = w * 4 + j_;                                                        \
      gload16(kh + (size_t)((KV0) + (ch_ >> 1) * 16 + lr) * 64 + (ch_ & 1) * 32 + lg * 8, \
              &Ks[BUF][ch_ * 512 + l * 8]);                                              \
    }                                                                                    \
  }

#define COMPUTE(BUF, DIAG, O, LPART, QF, QROW, KVB)                                      \
  {                                                                                      \
    const bf16* vbase_ = vh + (size_t)((KVB) >> 7) * 8192;                               \
    bf16x8 vf_[4][4];                                                                    \
    _Pragma("unroll") for (int c_ = 0; c_ < 4; c_++)                                     \
      _Pragma("unroll") for (int f_ = 0; f_ < 4; f_++)                                   \
        vf_[c_][f_] = *(const bf16x8*)&vbase_[(c_ * 4 + f_) * 512 + l * 8];              \
    bf16x8 kf_[8][2];                                                                    \
    _Pragma("unroll") for (int s_ = 0; s_ < 8; s_++)                                     \
      _Pragma("unroll") for (int c_ = 0; c_ < 2; c_++)                                   \
        kf_[s_][c_] = *(const bf16x8*)&Ks[BUF][(s_ * 2 + c_) * 512 + l * 8];             \
    f32x4 sa_[8] = {};                                                                   \
    __builtin_amdgcn_s_setprio(1);                                                       \
    _Pragma("unroll") for (int s_ = 0; s_ < 8; s_++) {                                   \
      sa_[s_] = __builtin_amdgcn_mfma_f32_16x16x32_bf16(kf_[s_][0], QF[0], sa_[s_], 0, 0, 0); \
      sa_[s_] = __builtin_amdgcn_mfma_f32_16x16x32_bf16(kf_[s_][1], QF[1], sa_[s_], 0, 0, 0); \
    }                                                                                    \
    __builtin_amdgcn_s_setprio(0);                                                       \
    bf16x8 pf_[4];                                                                       \
    float sum0_ = 0.0f, sum1_ = 0.0f;                                                    \
    _Pragma("unroll") for (int s_ = 0; s_ < 8; s_++)                                     \
      _Pragma("unroll") for (int r_ = 0; r_ < 4; r_++) {                                 \
        float sc_ = sa_[s_][r_];                                                         \
        if (DIAG) {                                                                      \
          int kk_ = (KVB) + s_ * 16 + lg * 4 + r_;                                       \
          sc_ = (kk_ <= (QROW)) ? sc_ : -1e30f;                                          \
        }                                                                                \
        float e_ = exp2f(sc_);                                                           \
        if (s_ & 1) sum1_ += e_; else sum0_ += e_;                                       \
        pf_[s_ >> 1][(s_ & 1) * 4 + r_] = (bf16)e_;                                      \
      }                                                                                  \
    LPART += sum0_ + sum1_;                                                              \
    __builtin_amdgcn_s_setprio(1);                                                       \
    _Pragma("unroll") for (int c_ = 0; c_ < 4; c_++)                                     \
      _Pragma("unroll") for (int f_ = 0; f_ < 4; f_++)                                   \
        O[c_] = __builtin_amdgcn_mfma_f32_16x16x32_bf16(vf_[c_][f_], pf_[f_], O[c_], 0, 0, 0); \
    __builtin_amdgcn_s_setprio(0);                                                       \
  }

#define EPILOG(O, LPART, Q0)                                                             \
  {                                                                                      \
    float lt_ = LPART;                                                                   \
    lt_ += __shfl_xor(lt_, 16);                                                          \
    lt_ += __shfl_xor(lt_, 32);                                                          \
    const float inv_ = 1.0f / lt_;                                                       \
    _Pragma("unroll") for (int c_ = 0; c_ < 4; c_++) {                                   \
      bf16x4 ov_;                                                                        \
      _Pragma("unroll") for (int r_ = 0; r_ < 4; r_++) ov_[r_] = (bf16)(O[c_][r_] * inv_); \
      size_t addr_ = ((size_t)(b * kS + (Q0) + lr)) * (kH * kD) + h * 64 + c_ * 16 + lg * 4; \
      *(bf16x4*)&ob[addr_] = ov_;                                                        \
    }                                                                                    \
  }

__global__ __launch_bounds__(256, 3) void attn_kernel(const bf16* __restrict__ qb,
                                                      const bf16* __restrict__ kb,
                                                      const bf16* __restrict__ vtb,
                                                      bf16* __restrict__ ob) {
  __shared__ bf16 Ks[2][8192];
  const int tid = threadIdx.x;
  const int w = tid >> 6, l = tid & 63;
  const int lr = l & 15, lg = l >> 4;
  const int bid = blockIdx.x;
  const int bh = bid & 31;                  // bid%8 keys XCD -> 4 bh per XCD (KV L2-resident)
  const int qt = 31 - (bid >> 5);           // heavy q-tiles dispatched first
  const bf16* qh = qb + (size_t)bh * (kS * kD);
  const bf16* kh = kb + (size_t)bh * (kS * kD);
  const bf16* vh = vtb + (size_t)bh * 131072;
  const int b = bh >> 4, h = bh & 15;

  const int q0 = qt * 64 + w * 16;
  const int q = q0 + lr;
  bf16x8 qf[2];
#pragma unroll
  for (int c = 0; c < 2; c++)
    qf[c] = *(const bf16x8*)&qh[(size_t)(q0 + lr) * kD + c * 32 + lg * 8];

  float lpart = 0.0f;
  f32x4 o[4] = {};
  const int nkv = (qt + 2) >> 1;            // kv tiles of 128

  STAGE(0, 0)
  __syncthreads();
  int cur = 0;
  for (int t = 0; t < nkv; t++) {
    if (t + 1 < nkv) STAGE(cur ^ 1, (t + 1) * 128)
    COMPUTE(cur, (t == nkv - 1), o, lpart, qf, q, t * 128)
    __syncthreads();
    cur ^= 1;
  }
  EPILOG(o, lpart, q0)
}

extern "C" void kernel_launch(void* const* d_in, const int* in_sizes, int n_in,
                              void* d_out, int out_size, void* d_ws, size_t ws_size,
                              hipStream_t stream) {
  const float* x  = (const float*)d_in[0];
  const float* wq = (const float*)d_in[1];
  const float* wk = (const float*)d_in[2];
  const float* wv = (const float*)d_in[3];
  const float* wo = (const float*)d_in[4];

  bf16* xb  = (bf16*)d_ws;            // 4M elems each (8 MiB)
  bf16* qb  = xb + (1 << 22);
  bf16* kb  = qb + (1 << 22);
  bf16* vtb = kb + (1 << 22);
  bf16* ab  = vtb + (1 << 22);
  bf16* wqb = ab + (1 << 22);         // 1M elems each (2 MiB)
  bf16* wkb = wqb + (1 << 20);
  bf16* wvb = wkb + (1 << 20);
  bf16* wob = wvb + (1 << 20);

  cast_all_kernel<<<4096, 256, 0, stream>>>(x, wq, wk, wv, wo, xb, wqb, wkb, wvb, wob);
  gemm_qkv<<<768, 256, 0, stream>>>(xb, wqb, wkb, wvb, qb, kb, vtb);
  attn_kernel<<<1024, 256, 0, stream>>>(qb, kb, vtb, ab);
  gemm_out<<<256, 256, 0, stream>>>(ab, wob, (float*)d_out);
}

// Round 20
// 111.733 us; speedup vs baseline: 1.1139x; 1.1139x over previous
//
#include <hip/hip_runtime.h>
#include <cstdint>
#include <cstddef>

typedef __bf16 bf16;
typedef __attribute__((ext_vector_type(8))) __bf16 bf16x8;
typedef __attribute__((ext_vector_type(4))) __bf16 bf16x4;
typedef __attribute__((ext_vector_type(4))) float f32x4;

constexpr int kS = 2048;
constexpr int kH = 16;
constexpr int kD = 64;

__device__ __forceinline__ void gload16(const bf16* g, bf16* l) {
  __builtin_amdgcn_global_load_lds((const __attribute__((address_space(1))) void*)g,
                                   (__attribute__((address_space(3))) void*)l, 16, 0, 0);
}

// ---------------- cast fp32 -> bf16 (x + 4 weights), 8 floats/thread ----------------
__global__ __launch_bounds__(256) void cast_all_kernel(
    const float* __restrict__ x, const float* __restrict__ wq, const float* __restrict__ wk,
    const float* __restrict__ wv, const float* __restrict__ wo,
    bf16* __restrict__ xb, bf16* __restrict__ wqb, bf16* __restrict__ wkb,
    bf16* __restrict__ wvb, bf16* __restrict__ wob) {
  int idx = blockIdx.x * 256 + threadIdx.x;   // 1M threads, 8 floats each
  const float* src; bf16* dst; int i;
  if (idx < (1 << 19)) { src = x; dst = xb; i = idx << 3; }
  else {
    int r = idx - (1 << 19);
    int t = r >> 17;
    i = (r & ((1 << 17) - 1)) << 3;
    src = (t == 0) ? wq : (t == 1) ? wk : (t == 2) ? wv : wo;
    dst = (t == 0) ? wqb : (t == 1) ? wkb : (t == 2) ? wvb : wob;
  }
  float4 v0 = *(const float4*)(src + i);
  float4 v1 = *(const float4*)(src + i + 4);
  bf16x8 o;
  o[0] = (bf16)v0.x; o[1] = (bf16)v0.y; o[2] = (bf16)v0.z; o[3] = (bf16)v0.w;
  o[4] = (bf16)v1.x; o[5] = (bf16)v1.y; o[6] = (bf16)v1.z; o[7] = (bf16)v1.w;
  *(bf16x8*)(dst + i) = o;
}

// PROVEN GEMM structure (r6/r8/r14) + r18 XCD-local remap. The "~490TF
// plateau" was L2-locality, not loop structure (r18: FETCH-fit -> +40%).
// r19 V-direct REJECTED: cross-XCD producer/consumer -> V reads miss L2
// (FETCH 12.3->18.6MB, attn 47.8->63us). K+V LDS-staged attn is the
// robust optimum for this structure.
// LDS granule swizzle: read quad (lr&1)*4+(lg^((lr>>1)&3)); source
// pre-permuted to match (conflicts=0).

#define GSTAGE(BUF, KT)                                    \
  gload16(aP0 + (KT), &As[BUF][(w * 64 + l) * 8]);         \
  gload16(aP1 + (KT), &As[BUF][((4 + w) * 64 + l) * 8]);   \
  gload16(bP0 + (KT), &Bs[BUF][(w * 64 + l) * 8]);         \
  gload16(bP1 + (KT), &Bs[BUF][((4 + w) * 64 + l) * 8]);

// ---------------- fused QKV GEMM + RoPE + layout transforms ----------------
// q: [B,H,S,D]; k: [B,H,S,D] PRE-SCALED by 0.125*log2(e) (softmax fold);
// v: [B,H,D,S] with 32-chunk MFMA permutation.
// r18 remap: XCD x owns an (8-mblk x 4-npanel) rectangle across all 3
// outputs -> per-XCD working set 5MB. Bijective on 768 blocks.
__global__ __launch_bounds__(256) void gemm_qkv(const bf16* __restrict__ A,
                                                const bf16* __restrict__ wq,
                                                const bf16* __restrict__ wk,
                                                const bf16* __restrict__ wv,
                                                bf16* __restrict__ qo,
                                                bf16* __restrict__ ko,
                                                bf16* __restrict__ vto) {
  __shared__ bf16 As[2][128 * 32];
  __shared__ bf16 Bs[2][128 * 32];
  const int tid = threadIdx.x;
  const int w = tid >> 6, l = tid & 63;
  const int wr = w >> 1, wc = w & 1;
  const int lr = l & 15, lg = l >> 4;

  const int xcd = blockIdx.x & 7;
  const int idx = blockIdx.x >> 3;          // 0..95 within XCD
  const int which = idx >> 5;               // 0=q 1=k 2=v
  const int rem = idx & 31;
  const int mblk = ((xcd >> 1) << 3) + (rem >> 2);
  const int npanel = ((xcd & 1) << 2) + (rem & 3);
  const int m0 = mblk * 128;
  const int n0 = npanel * 128;
  const bf16* Bw = (which == 0) ? wq : (which == 1) ? wk : wv;

  const int srow = l >> 2;
  const int skcol = ((l & 3) ^ ((l >> 3) & 3)) << 3;   // swizzled source chunk
  const int K = 1024;

  const bf16* aP0 = A + (size_t)(m0 + w * 16 + srow) * K + skcol;
  const bf16* aP1 = A + (size_t)(m0 + 64 + w * 16 + srow) * K + skcol;
  const bf16* bP0 = Bw + (size_t)(n0 + w * 16 + srow) * K + skcol;
  const bf16* bP1 = Bw + (size_t)(n0 + 64 + w * 16 + srow) * K + skcol;

  f32x4 acc[4][4] = {};
  const int ca = (lg ^ ((lr >> 1) & 3)) * 8;           // swizzled read chunk

  GSTAGE(0, 0)
  __syncthreads();
  int cur = 0;
  for (int kt = 0; kt < K; kt += 32) {
    if (kt + 32 < K) { GSTAGE(cur ^ 1, kt + 32) }
    bf16x8 af[4], bfg[4];
#pragma unroll
    for (int mi = 0; mi < 4; mi++)
      af[mi] = *(const bf16x8*)&As[cur][(wr * 64 + mi * 16 + lr) * 32 + ca];
#pragma unroll
    for (int ni = 0; ni < 4; ni++)
      bfg[ni] = *(const bf16x8*)&Bs[cur][(wc * 64 + ni * 16 + lr) * 32 + ca];
    __builtin_amdgcn_s_setprio(1);
#pragma unroll
    for (int mi = 0; mi < 4; mi++)
#pragma unroll
      for (int ni = 0; ni < 4; ni++)
        acc[mi][ni] = __builtin_amdgcn_mfma_f32_16x16x32_bf16(af[mi], bfg[ni], acc[mi][ni], 0, 0, 0);
    __builtin_amdgcn_s_setprio(0);
    __syncthreads();
    cur ^= 1;
  }

  float invf_[4];
#pragma unroll
  for (int ni = 0; ni < 4; ni++) {
    int d31 = ((n0 + wc * 64 + ni * 16 + lr) & 63) & 31;
    invf_[ni] = exp2f((float)d31 * -0.41524100480466348f);   // 10000^(-(d&31)/32)
  }

#pragma unroll
  for (int mi = 0; mi < 4; mi++) {
#pragma unroll
    for (int ni = 0; ni < 4; ni++) {
#pragma unroll
      for (int r = 0; r < 4; r++) {
        const int m = m0 + wr * 64 + mi * 16 + lg * 4 + r;   // token index
        const int n = n0 + wc * 64 + ni * 16 + lr;           // emb index (h*64+d)
        float v = acc[mi][ni][r];
        const int st = m & 2047;                              // seq position
        const size_t bh = (size_t)(m >> 11) * kH + (n >> 6);
        if (which < 2) {
          float vp = __shfl_xor(v, 1);
          const int d = n & 63;
          float th = (float)st * invf_[ni];
          float sth = __sinf(th), cth = __cosf(th);
          float rv = v * cth + ((d & 1) ? vp : -vp) * sth;
          if (which == 1) rv *= 0.18033688011112042f;        // 0.125*log2(e): softmax fold
          bf16* dst = which ? ko : qo;                       // [B,H,S,D]
          dst[((bh << 11) + st) * kD + d] = (bf16)rv;
        } else {                                             // [B,H,D,S] permuted
          int pos = (st & ~31) | (((st >> 2) & 3) << 3) | (((st >> 4) & 1) << 2) | (st & 3);
          vto[((bh * kD + (n & 63)) << 11) + pos] = (bf16)v;
        }
      }
    }
  }
}

// ---------------- final GEMM C = A @ Wo^T, fp32 out ----------------
// r17 XCD-locality remap (proven): XCD owns m-rows [4x,4x+4) x all 8
// n-panels -> 3MB L2-fit.
__global__ __launch_bounds__(256) void gemm_out(const bf16* __restrict__ A,
                                                const bf16* __restrict__ Bw,
                                                float* __restrict__ Cout) {
  __shared__ bf16 As[2][128 * 32];
  __shared__ bf16 Bs[2][128 * 32];
  const int tid = threadIdx.x;
  const int w = tid >> 6, l = tid & 63;
  const int wr = w >> 1, wc = w & 1;
  const int lr = l & 15, lg = l >> 4;
  const int bid = blockIdx.x;
  const int m0 = (((bid & 7) << 2) + ((bid >> 3) >> 3)) * 128;   // XCD owns 4 m-rows
  const int n0 = ((bid >> 3) & 7) * 128;
  const int K = 1024, N = 1024;

  const int srow = l >> 2;
  const int skcol = ((l & 3) ^ ((l >> 3) & 3)) << 3;

  const bf16* aP0 = A + (size_t)(m0 + w * 16 + srow) * K + skcol;
  const bf16* aP1 = A + (size_t)(m0 + 64 + w * 16 + srow) * K + skcol;
  const bf16* bP0 = Bw + (size_t)(n0 + w * 16 + srow) * K + skcol;
  const bf16* bP1 = Bw + (size_t)(n0 + 64 + w * 16 + srow) * K + skcol;

  f32x4 acc[4][4] = {};
  const int ca = (lg ^ ((lr >> 1) & 3)) * 8;

  GSTAGE(0, 0)
  __syncthreads();
  int cur = 0;
  for (int kt = 0; kt < K; kt += 32) {
    if (kt + 32 < K) { GSTAGE(cur ^ 1, kt + 32) }
    bf16x8 af[4], bfg[4];
#pragma unroll
    for (int mi = 0; mi < 4; mi++)
      af[mi] = *(const bf16x8*)&As[cur][(wr * 64 + mi * 16 + lr) * 32 + ca];
#pragma unroll
    for (int ni = 0; ni < 4; ni++)
      bfg[ni] = *(const bf16x8*)&Bs[cur][(wc * 64 + ni * 16 + lr) * 32 + ca];
    __builtin_amdgcn_s_setprio(1);
#pragma unroll
    for (int mi = 0; mi < 4; mi++)
#pragma unroll
      for (int ni = 0; ni < 4; ni++)
        acc[mi][ni] = __builtin_amdgcn_mfma_f32_16x16x32_bf16(af[mi], bfg[ni], acc[mi][ni], 0, 0, 0);
    __builtin_amdgcn_s_setprio(0);
    __syncthreads();
    cur ^= 1;
  }

#pragma unroll
  for (int mi = 0; mi < 4; mi++)
#pragma unroll
    for (int ni = 0; ni < 4; ni++)
#pragma unroll
      for (int r = 0; r < 4; r++) {
        const int m = m0 + wr * 64 + mi * 16 + lg * 4 + r;
        const int n = n0 + wc * 64 + ni * 16 + lr;
        Cout[(size_t)m * N + n] = acc[mi][ni][r];
      }
}

// ---------------- flash attention, causal, KVBLK=128 (r18 proven best) ----------------
#define STAGE(BUF, KV0)                                                                  \
  {                                                                                      \
    _Pragma("unroll") for (int j_ = 0; j_ < 4; j_++) {                                   \
      const int ch_ = w * 4 + j_;                                                        \
      gload16(kh + (size_t)((KV0) + (ch_ >> 1) * 16 + lr) * 64 + (ch_ & 1) * 32 + lg * 8, \
              &Ks[BUF][ch_ * 512 + l * 8]);                                              \
    }                                                                                    \
    _Pragma("unroll") for (int j_ = 0; j_ < 4; j_++) {                                   \
      const int ch_ = w * 4 + j_;                                                        \
      gload16(vh + (size_t)((ch_ >> 2) * 16 + lr) * 2048 + (KV0) + (ch_ & 3) * 32 + lg * 8, \
              &Vs[BUF][ch_ * 512 + l * 8]);                                              \
    }                                                                                    \
  }

#define COMPUTE(BUF, DIAG, O, LPART, QF, QROW, KVB)                                      \
  {                                                                                      \
    bf16x8 kf_[8][2];                                                                    \
    _Pragma("unroll") for (int s_ = 0; s_ < 8; s_++)                                     \
      _Pragma("unroll") for (int c_ = 0; c_ < 2; c_++)                                   \
        kf_[s_][c_] = *(const bf16x8*)&Ks[BUF][(s_ * 2 + c_) * 512 + l * 8];             \
    f32x4 sa_[8] = {};                                                                   \
    __builtin_amdgcn_s_setprio(1);                                                       \
    _Pragma("unroll") for (int s_ = 0; s_ < 8; s_++) {                                   \
      sa_[s_] = __builtin_amdgcn_mfma_f32_16x16x32_bf16(kf_[s_][0], QF[0], sa_[s_], 0, 0, 0); \
      sa_[s_] = __builtin_amdgcn_mfma_f32_16x16x32_bf16(kf_[s_][1], QF[1], sa_[s_], 0, 0, 0); \
    }                                                                                    \
    __builtin_amdgcn_s_setprio(0);                                                       \
    bf16x8 pf_[4];                                                                       \
    float sum0_ = 0.0f, sum1_ = 0.0f;                                                    \
    _Pragma("unroll") for (int s_ = 0; s_ < 8; s_++)                                     \
      _Pragma("unroll") for (int r_ = 0; r_ < 4; r_++) {                                 \
        float sc_ = sa_[s_][r_];                                                         \
        if (DIAG) {                                                                      \
          int kk_ = (KVB) + s_ * 16 + lg * 4 + r_;                                       \
          sc_ = (kk_ <= (QROW)) ? sc_ : -1e30f;                                          \
        }                                                                                \
        float e_ = exp2f(sc_);                                                           \
        if (s_ & 1) sum1_ += e_; else sum0_ += e_;                                       \
        pf_[s_ >> 1][(s_ & 1) * 4 + r_] = (bf16)e_;                                      \
      }                                                                                  \
    LPART += sum0_ + sum1_;                                                              \
    bf16x8 vf_[4][4];                                                                    \
    _Pragma("unroll") for (int c_ = 0; c_ < 4; c_++)                                     \
      _Pragma("unroll") for (int f_ = 0; f_ < 4; f_++)                                   \
        vf_[c_][f_] = *(const bf16x8*)&Vs[BUF][(c_ * 4 + f_) * 512 + l * 8];             \
    __builtin_amdgcn_s_setprio(1);                                                       \
    _Pragma("unroll") for (int c_ = 0; c_ < 4; c_++)                                     \
      _Pragma("unroll") for (int f_ = 0; f_ < 4; f_++)                                   \
        O[c_] = __builtin_amdgcn_mfma_f32_16x16x32_bf16(vf_[c_][f_], pf_[f_], O[c_], 0, 0, 0); \
    __builtin_amdgcn_s_setprio(0);                                                       \
  }

#define EPILOG(O, LPART, Q0)                                                             \
  {                                                                                      \
    float lt_ = LPART;                                                                   \
    lt_ += __shfl_xor(lt_, 16);                                                          \
    lt_ += __shfl_xor(lt_, 32);                                                          \
    const float inv_ = 1.0f / lt_;                                                       \
    _Pragma("unroll") for (int c_ = 0; c_ < 4; c_++) {                                   \
      bf16x4 ov_;                                                                        \
      _Pragma("unroll") for (int r_ = 0; r_ < 4; r_++) ov_[r_] = (bf16)(O[c_][r_] * inv_); \
      size_t addr_ = ((size_t)(b * kS + (Q0) + lr)) * (kH * kD) + h * 64 + c_ * 16 + lg * 4; \
      *(bf16x4*)&ob[addr_] = ov_;                                                        \
    }                                                                                    \
  }

__global__ __launch_bounds__(256, 2) void attn_kernel(const bf16* __restrict__ qb,
                                                      const bf16* __restrict__ kb,
                                                      const bf16* __restrict__ vtb,
                                                      bf16* __restrict__ ob) {
  __shared__ bf16 Ks[2][8192];
  __shared__ bf16 Vs[2][8192];
  const int tid = threadIdx.x;
  const int w = tid >> 6, l = tid & 63;
  const int lr = l & 15, lg = l >> 4;
  const int bid = blockIdx.x;
  const int bh = bid & 31;                  // bid%8 keys XCD -> 4 bh per XCD (2MB KV in L2)
  const int qt = 31 - (bid >> 5);           // heavy q-tiles dispatched first
  const bf16* qh = qb + (size_t)bh * (kS * kD);
  const bf16* kh = kb + (size_t)bh * (kS * kD);
  const bf16* vh = vtb + (size_t)bh * (kS * kD);
  const int b = bh >> 4, h = bh & 15;

  const int q0 = qt * 64 + w * 16;
  const int q = q0 + lr;
  bf16x8 qf[2];
#pragma unroll
  for (int c = 0; c < 2; c++)
    qf[c] = *(const bf16x8*)&qh[(size_t)(q0 + lr) * kD + c * 32 + lg * 8];

  float lpart = 0.0f;
  f32x4 o[4] = {};
  const int nkv = (qt + 2) >> 1;            // kv tiles of 128

  STAGE(0, 0)
  __syncthreads();
  int cur = 0;
  for (int t = 0; t < nkv; t++) {
    if (t + 1 < nkv) STAGE(cur ^ 1, (t + 1) * 128)
    COMPUTE(cur, (t == nkv - 1), o, lpart, qf, q, t * 128)
    __syncthreads();
    cur ^= 1;
  }
  EPILOG(o, lpart, q0)
}

extern "C" void kernel_launch(void* const* d_in, const int* in_sizes, int n_in,
                              void* d_out, int out_size, void* d_ws, size_t ws_size,
                              hipStream_t stream) {
  const float* x  = (const float*)d_in[0];
  const float* wq = (const float*)d_in[1];
  const float* wk = (const float*)d_in[2];
  const float* wv = (const float*)d_in[3];
  const float* wo = (const float*)d_in[4];

  bf16* xb  = (bf16*)d_ws;            // 4M elems each (8 MiB)
  bf16* qb  = xb + (1 << 22);
  bf16* kb  = qb + (1 << 22);
  bf16* vtb = kb + (1 << 22);
  bf16* ab  = vtb + (1 << 22);
  bf16* wqb = ab + (1 << 22);         // 1M elems each (2 MiB)
  bf16* wkb = wqb + (1 << 20);
  bf16* wvb = wkb + (1 << 20);
  bf16* wob = wvb + (1 << 20);

  cast_all_kernel<<<4096, 256, 0, stream>>>(x, wq, wk, wv, wo, xb, wqb, wkb, wvb, wob);
  gemm_qkv<<<768, 256, 0, stream>>>(xb, wqb, wkb, wvb, qb, kb, vtb);
  attn_kernel<<<1024, 256, 0, stream>>>(qb, kb, vtb, ab);
  gemm_out<<<256, 256, 0, stream>>>(ab, wob, (float*)d_out);
}

// Round 21
// 108.510 us; speedup vs baseline: 1.1470x; 1.0297x over previous
//
#include <hip/hip_runtime.h>
#include <cstdint>
#include <cstddef>

typedef __bf16 bf16;
typedef __attribute__((ext_vector_type(8))) __bf16 bf16x8;
typedef __attribute__((ext_vector_type(4))) __bf16 bf16x4;
typedef __attribute__((ext_vector_type(4))) float f32x4;

constexpr int kS = 2048;
constexpr int kH = 16;
constexpr int kD = 64;

__device__ __forceinline__ void gload16(const bf16* g, bf16* l) {
  __builtin_amdgcn_global_load_lds((const __attribute__((address_space(1))) void*)g,
                                   (__attribute__((address_space(3))) void*)l, 16, 0, 0);
}

// ---------------- cast fp32 -> bf16 (x + 4 weights), 8 floats/thread ----------------
__global__ __launch_bounds__(256) void cast_all_kernel(
    const float* __restrict__ x, const float* __restrict__ wq, const float* __restrict__ wk,
    const float* __restrict__ wv, const float* __restrict__ wo,
    bf16* __restrict__ xb, bf16* __restrict__ wqb, bf16* __restrict__ wkb,
    bf16* __restrict__ wvb, bf16* __restrict__ wob) {
  int idx = blockIdx.x * 256 + threadIdx.x;   // 1M threads, 8 floats each
  const float* src; bf16* dst; int i;
  if (idx < (1 << 19)) { src = x; dst = xb; i = idx << 3; }
  else {
    int r = idx - (1 << 19);
    int t = r >> 17;
    i = (r & ((1 << 17) - 1)) << 3;
    src = (t == 0) ? wq : (t == 1) ? wk : (t == 2) ? wv : wo;
    dst = (t == 0) ? wqb : (t == 1) ? wkb : (t == 2) ? wvb : wob;
  }
  float4 v0 = *(const float4*)(src + i);
  float4 v1 = *(const float4*)(src + i + 4);
  bf16x8 o;
  o[0] = (bf16)v0.x; o[1] = (bf16)v0.y; o[2] = (bf16)v0.z; o[3] = (bf16)v0.w;
  o[4] = (bf16)v1.x; o[5] = (bf16)v1.y; o[6] = (bf16)v1.z; o[7] = (bf16)v1.w;
  *(bf16x8*)(dst + i) = o;
}

// PROVEN GEMM structure (r6/r8/r14) + r18 XCD-local remap. The "~490TF
// plateau" was L2-locality (r18: FETCH-fit -> +40%); post-fix, co-residency
// matters too (qkv 3/CU = 678TF vs out 1/CU = 554TF on identical body ->
// r21 splits gemm_out to 2+/CU).
// r19 V-direct REJECTED: cross-XCD producer/consumer -> V reads miss L2.
// LDS granule swizzle: read quad (lr&1)*4+(lg^((lr>>1)&3)); source
// pre-permuted to match (conflicts=0).

#define GSTAGE(BUF, KT)                                    \
  gload16(aP0 + (KT), &As[BUF][(w * 64 + l) * 8]);         \
  gload16(aP1 + (KT), &As[BUF][((4 + w) * 64 + l) * 8]);   \
  gload16(bP0 + (KT), &Bs[BUF][(w * 64 + l) * 8]);         \
  gload16(bP1 + (KT), &Bs[BUF][((4 + w) * 64 + l) * 8]);

// ---------------- fused QKV GEMM + RoPE + layout transforms ----------------
// q: [B,H,S,D]; k: [B,H,S,D] PRE-SCALED by 0.125*log2(e) (softmax fold);
// v: [B,H,D,S] with 32-chunk MFMA permutation.
// r18 remap: XCD x owns an (8-mblk x 4-npanel) rectangle across all 3
// outputs -> per-XCD working set 5MB. Bijective on 768 blocks.
__global__ __launch_bounds__(256) void gemm_qkv(const bf16* __restrict__ A,
                                                const bf16* __restrict__ wq,
                                                const bf16* __restrict__ wk,
                                                const bf16* __restrict__ wv,
                                                bf16* __restrict__ qo,
                                                bf16* __restrict__ ko,
                                                bf16* __restrict__ vto) {
  __shared__ bf16 As[2][128 * 32];
  __shared__ bf16 Bs[2][128 * 32];
  const int tid = threadIdx.x;
  const int w = tid >> 6, l = tid & 63;
  const int wr = w >> 1, wc = w & 1;
  const int lr = l & 15, lg = l >> 4;

  const int xcd = blockIdx.x & 7;
  const int idx = blockIdx.x >> 3;          // 0..95 within XCD
  const int which = idx >> 5;               // 0=q 1=k 2=v
  const int rem = idx & 31;
  const int mblk = ((xcd >> 1) << 3) + (rem >> 2);
  const int npanel = ((xcd & 1) << 2) + (rem & 3);
  const int m0 = mblk * 128;
  const int n0 = npanel * 128;
  const bf16* Bw = (which == 0) ? wq : (which == 1) ? wk : wv;

  const int srow = l >> 2;
  const int skcol = ((l & 3) ^ ((l >> 3) & 3)) << 3;   // swizzled source chunk
  const int K = 1024;

  const bf16* aP0 = A + (size_t)(m0 + w * 16 + srow) * K + skcol;
  const bf16* aP1 = A + (size_t)(m0 + 64 + w * 16 + srow) * K + skcol;
  const bf16* bP0 = Bw + (size_t)(n0 + w * 16 + srow) * K + skcol;
  const bf16* bP1 = Bw + (size_t)(n0 + 64 + w * 16 + srow) * K + skcol;

  f32x4 acc[4][4] = {};
  const int ca = (lg ^ ((lr >> 1) & 3)) * 8;           // swizzled read chunk

  GSTAGE(0, 0)
  __syncthreads();
  int cur = 0;
  for (int kt = 0; kt < K; kt += 32) {
    if (kt + 32 < K) { GSTAGE(cur ^ 1, kt + 32) }
    bf16x8 af[4], bfg[4];
#pragma unroll
    for (int mi = 0; mi < 4; mi++)
      af[mi] = *(const bf16x8*)&As[cur][(wr * 64 + mi * 16 + lr) * 32 + ca];
#pragma unroll
    for (int ni = 0; ni < 4; ni++)
      bfg[ni] = *(const bf16x8*)&Bs[cur][(wc * 64 + ni * 16 + lr) * 32 + ca];
    __builtin_amdgcn_s_setprio(1);
#pragma unroll
    for (int mi = 0; mi < 4; mi++)
#pragma unroll
      for (int ni = 0; ni < 4; ni++)
        acc[mi][ni] = __builtin_amdgcn_mfma_f32_16x16x32_bf16(af[mi], bfg[ni], acc[mi][ni], 0, 0, 0);
    __builtin_amdgcn_s_setprio(0);
    __syncthreads();
    cur ^= 1;
  }

  float invf_[4];
#pragma unroll
  for (int ni = 0; ni < 4; ni++) {
    int d31 = ((n0 + wc * 64 + ni * 16 + lr) & 63) & 31;
    invf_[ni] = exp2f((float)d31 * -0.41524100480466348f);   // 10000^(-(d&31)/32)
  }

#pragma unroll
  for (int mi = 0; mi < 4; mi++) {
#pragma unroll
    for (int ni = 0; ni < 4; ni++) {
#pragma unroll
      for (int r = 0; r < 4; r++) {
        const int m = m0 + wr * 64 + mi * 16 + lg * 4 + r;   // token index
        const int n = n0 + wc * 64 + ni * 16 + lr;           // emb index (h*64+d)
        float v = acc[mi][ni][r];
        const int st = m & 2047;                              // seq position
        const size_t bh = (size_t)(m >> 11) * kH + (n >> 6);
        if (which < 2) {
          float vp = __shfl_xor(v, 1);
          const int d = n & 63;
          float th = (float)st * invf_[ni];
          float sth = __sinf(th), cth = __cosf(th);
          float rv = v * cth + ((d & 1) ? vp : -vp) * sth;
          if (which == 1) rv *= 0.18033688011112042f;        // 0.125*log2(e): softmax fold
          bf16* dst = which ? ko : qo;                       // [B,H,S,D]
          dst[((bh << 11) + st) * kD + d] = (bf16)rv;
        } else {                                             // [B,H,D,S] permuted
          int pos = (st & ~31) | (((st >> 2) & 3) << 3) | (((st >> 4) & 1) << 2) | (st & 3);
          vto[((bh * kD + (n & 63)) << 11) + pos] = (bf16)v;
        }
      }
    }
  }
}

// ---------------- final GEMM C = A @ Wo^T, fp32 out ----------------
// r21: 64x128 tiles -> 512 blocks (2+/CU co-resident; was 1/CU, which left
// barrier drains unoverlapped: out 554TF vs qkv 678TF on identical body).
// XCD map: XCD x owns m-rows [512x,512x+512) x all 8 n-panels -> 1MB A-slice
// + 2MB Wo, L2-fit (r17 principle). LDS 24KB.
__global__ __launch_bounds__(256) void gemm_out(const bf16* __restrict__ A,
                                                const bf16* __restrict__ Bw,
                                                float* __restrict__ Cout) {
  __shared__ bf16 As[2][64 * 32];
  __shared__ bf16 Bs[2][128 * 32];
  const int tid = threadIdx.x;
  const int w = tid >> 6, l = tid & 63;
  const int wr = w >> 1, wc = w & 1;
  const int lr = l & 15, lg = l >> 4;
  const int bid = blockIdx.x;
  const int xcd = bid & 7;
  const int r5 = bid >> 3;                  // 0..63
  const int m0 = (((xcd << 3) + (r5 >> 3))) * 64;   // 64-row m-block
  const int n0 = (r5 & 7) * 128;
  const int K = 1024, N = 1024;

  const int srow = l >> 2;
  const int skcol = ((l & 3) ^ ((l >> 3) & 3)) << 3;

  const bf16* aP0 = A + (size_t)(m0 + w * 16 + srow) * K + skcol;
  const bf16* bP0 = Bw + (size_t)(n0 + w * 16 + srow) * K + skcol;
  const bf16* bP1 = Bw + (size_t)(n0 + 64 + w * 16 + srow) * K + skcol;

  f32x4 acc[2][4] = {};
  const int ca = (lg ^ ((lr >> 1) & 3)) * 8;

#define OSTAGE(BUF, KT)                                    \
  gload16(aP0 + (KT), &As[BUF][(w * 64 + l) * 8]);         \
  gload16(bP0 + (KT), &Bs[BUF][(w * 64 + l) * 8]);         \
  gload16(bP1 + (KT), &Bs[BUF][((4 + w) * 64 + l) * 8]);

  OSTAGE(0, 0)
  __syncthreads();
  int cur = 0;
  for (int kt = 0; kt < K; kt += 32) {
    if (kt + 32 < K) { OSTAGE(cur ^ 1, kt + 32) }
    bf16x8 af[2], bfg[4];
#pragma unroll
    for (int mi = 0; mi < 2; mi++)
      af[mi] = *(const bf16x8*)&As[cur][(wr * 32 + mi * 16 + lr) * 32 + ca];
#pragma unroll
    for (int ni = 0; ni < 4; ni++)
      bfg[ni] = *(const bf16x8*)&Bs[cur][(wc * 64 + ni * 16 + lr) * 32 + ca];
    __builtin_amdgcn_s_setprio(1);
#pragma unroll
    for (int mi = 0; mi < 2; mi++)
#pragma unroll
      for (int ni = 0; ni < 4; ni++)
        acc[mi][ni] = __builtin_amdgcn_mfma_f32_16x16x32_bf16(af[mi], bfg[ni], acc[mi][ni], 0, 0, 0);
    __builtin_amdgcn_s_setprio(0);
    __syncthreads();
    cur ^= 1;
  }
#undef OSTAGE

#pragma unroll
  for (int mi = 0; mi < 2; mi++)
#pragma unroll
    for (int ni = 0; ni < 4; ni++)
#pragma unroll
      for (int r = 0; r < 4; r++) {
        const int m = m0 + wr * 32 + mi * 16 + lg * 4 + r;
        const int n = n0 + wc * 64 + ni * 16 + lr;
        Cout[(size_t)m * N + n] = acc[mi][ni][r];
      }
}

// ---------------- flash attention, causal, KVBLK=128 (r18/r20 proven best) ----------------
#define STAGE(BUF, KV0)                                                                  \
  {                                                                                      \
    _Pragma("unroll") for (int j_ = 0; j_ < 4; j_++) {                                   \
      const int ch_ = w * 4 + j_;                                                        \
      gload16(kh + (size_t)((KV0) + (ch_ >> 1) * 16 + lr) * 64 + (ch_ & 1) * 32 + lg * 8, \
              &Ks[BUF][ch_ * 512 + l * 8]);                                              \
    }                                                                                    \
    _Pragma("unroll") for (int j_ = 0; j_ < 4; j_++) {                                   \
      const int ch_ = w * 4 + j_;                                                        \
      gload16(vh + (size_t)((ch_ >> 2) * 16 + lr) * 2048 + (KV0) + (ch_ & 3) * 32 + lg * 8, \
              &Vs[BUF][ch_ * 512 + l * 8]);                                              \
    }                                                                                    \
  }

#define COMPUTE(BUF, DIAG, O, LPART, QF, QROW, KVB)                                      \
  {                                                                                      \
    bf16x8 kf_[8][2];                                                                    \
    _Pragma("unroll") for (int s_ = 0; s_ < 8; s_++)                                     \
      _Pragma("unroll") for (int c_ = 0; c_ < 2; c_++)                                   \
        kf_[s_][c_] = *(const bf16x8*)&Ks[BUF][(s_ * 2 + c_) * 512 + l * 8];             \
    f32x4 sa_[8] = {};                                                                   \
    __builtin_amdgcn_s_setprio(1);                                                       \
    _Pragma("unroll") for (int s_ = 0; s_ < 8; s_++) {                                   \
      sa_[s_] = __builtin_amdgcn_mfma_f32_16x16x32_bf16(kf_[s_][0], QF[0], sa_[s_], 0, 0, 0); \
      sa_[s_] = __builtin_amdgcn_mfma_f32_16x16x32_bf16(kf_[s_][1], QF[1], sa_[s_], 0, 0, 0); \
    }                                                                                    \
    __builtin_amdgcn_s_setprio(0);                                                       \
    bf16x8 pf_[4];                                                                       \
    float sum0_ = 0.0f, sum1_ = 0.0f;                                                    \
    _Pragma("unroll") for (int s_ = 0; s_ < 8; s_++)                                     \
      _Pragma("unroll") for (int r_ = 0; r_ < 4; r_++) {                                 \
        float sc_ = sa_[s_][r_];                                                         \
        if (DIAG) {                                                                      \
          int kk_ = (KVB) + s_ * 16 + lg * 4 + r_;                                       \
          sc_ = (kk_ <= (QROW)) ? sc_ : -1e30f;                                          \
        }                                                                                \
        float e_ = exp2f(sc_);                                                           \
        if (s_ & 1) sum1_ += e_; else sum0_ += e_;                                       \
        pf_[s_ >> 1][(s_ & 1) * 4 + r_] = (bf16)e_;                                      \
      }                                                                                  \
    LPART += sum0_ + sum1_;                                                              \
    bf16x8 vf_[4][4];                                                                    \
    _Pragma("unroll") for (int c_ = 0; c_ < 4; c_++)                                     \
      _Pragma("unroll") for (int f_ = 0; f_ < 4; f_++)                                   \
        vf_[c_][f_] = *(const bf16x8*)&Vs[BUF][(c_ * 4 + f_) * 512 + l * 8];             \
    __builtin_amdgcn_s_setprio(1);                                                       \
    _Pragma("unroll") for (int c_ = 0; c_ < 4; c_++)                                     \
      _Pragma("unroll") for (int f_ = 0; f_ < 4; f_++)                                   \
        O[c_] = __builtin_amdgcn_mfma_f32_16x16x32_bf16(vf_[c_][f_], pf_[f_], O[c_], 0, 0, 0); \
    __builtin_amdgcn_s_setprio(0);                                                       \
  }

#define EPILOG(O, LPART, Q0)                                                             \
  {                                                                                      \
    float lt_ = LPART;                                                                   \
    lt_ += __shfl_xor(lt_, 16);                                                          \
    lt_ += __shfl_xor(lt_, 32);                                                          \
    const float inv_ = 1.0f / lt_;                                                       \
    _Pragma("unroll") for (int c_ = 0; c_ < 4; c_++) {                                   \
      bf16x4 ov_;                                                                        \
      _Pragma("unroll") for (int r_ = 0; r_ < 4; r_++) ov_[r_] = (bf16)(O[c_][r_] * inv_); \
      size_t addr_ = ((size_t)(b * kS + (Q0) + lr)) * (kH * kD) + h * 64 + c_ * 16 + lg * 4; \
      *(bf16x4*)&ob[addr_] = ov_;                                                        \
    }                                                                                    \
  }

__global__ __launch_bounds__(256, 2) void attn_kernel(const bf16* __restrict__ qb,
                                                      const bf16* __restrict__ kb,
                                                      const bf16* __restrict__ vtb,
                                                      bf16* __restrict__ ob) {
  __shared__ bf16 Ks[2][8192];
  __shared__ bf16 Vs[2][8192];
  const int tid = threadIdx.x;
  const int w = tid >> 6, l = tid & 63;
  const int lr = l & 15, lg = l >> 4;
  const int bid = blockIdx.x;
  const int bh = bid & 31;                  // bid%8 keys XCD -> 4 bh per XCD (2MB KV in L2)
  const int qt = 31 - (bid >> 5);           // heavy q-tiles dispatched first
  const bf16* qh = qb + (size_t)bh * (kS * kD);
  const bf16* kh = kb + (size_t)bh * (kS * kD);
  const bf16* vh = vtb + (size_t)bh * (kS * kD);
  const int b = bh >> 4, h = bh & 15;

  const int q0 = qt * 64 + w * 16;
  const int q = q0 + lr;
  bf16x8 qf[2];
#pragma unroll
  for (int c = 0; c < 2; c++)
    qf[c] = *(const bf16x8*)&qh[(size_t)(q0 + lr) * kD + c * 32 + lg * 8];

  float lpart = 0.0f;
  f32x4 o[4] = {};
  const int nkv = (qt + 2) >> 1;            // kv tiles of 128

  STAGE(0, 0)
  __syncthreads();
  int cur = 0;
  for (int t = 0; t < nkv; t++) {
    if (t + 1 < nkv) STAGE(cur ^ 1, (t + 1) * 128)
    COMPUTE(cur, (t == nkv - 1), o, lpart, qf, q, t * 128)
    __syncthreads();
    cur ^= 1;
  }
  EPILOG(o, lpart, q0)
}

extern "C" void kernel_launch(void* const* d_in, const int* in_sizes, int n_in,
                              void* d_out, int out_size, void* d_ws, size_t ws_size,
                              hipStream_t stream) {
  const float* x  = (const float*)d_in[0];
  const float* wq = (const float*)d_in[1];
  const float* wk = (const float*)d_in[2];
  const float* wv = (const float*)d_in[3];
  const float* wo = (const float*)d_in[4];

  bf16* xb  = (bf16*)d_ws;            // 4M elems each (8 MiB)
  bf16* qb  = xb + (1 << 22);
  bf16* kb  = qb + (1 << 22);
  bf16* vtb = kb + (1 << 22);
  bf16* ab  = vtb + (1 << 22);
  bf16* wqb = ab + (1 << 22);         // 1M elems each (2 MiB)
  bf16* wkb = wqb + (1 << 20);
  bf16* wvb = wkb + (1 << 20);
  bf16* wob = wvb + (1 << 20);

  cast_all_kernel<<<4096, 256, 0, stream>>>(x, wq, wk, wv, wo, xb, wqb, wkb, wvb, wob);
  gemm_qkv<<<768, 256, 0, stream>>>(xb, wqb, wkb, wvb, qb, kb, vtb);
  attn_kernel<<<1024, 256, 0, stream>>>(qb, kb, vtb, ab);
  gemm_out<<<512, 256, 0, stream>>>(ab, wob, (float*)d_out);
}